// Round 8
// baseline (547.813 us; speedup 1.0000x reference)
//
#include <hip/hip_runtime.h>
#include <hip/hip_bf16.h>

typedef __bf16 bf16;
typedef __attribute__((ext_vector_type(8))) __bf16 bf16x8;
typedef __attribute__((ext_vector_type(4))) float f32x4;

#define GLOAD_LDS16(g, l)                                                        \
    __builtin_amdgcn_global_load_lds(                                            \
        (const __attribute__((address_space(1))) void*)(g),                      \
        (__attribute__((address_space(3))) void*)(l), 16, 0, 0)

// ---------------- fp32 -> bf16 conversion (vectorized, grid-stride) ----------------
__global__ __launch_bounds__(256) void cvt_f32_bf16(
    const float* __restrict__ src, bf16* __restrict__ dst, int n16)
{
    int idx = blockIdx.x * 256 + threadIdx.x;
    const int stride = gridDim.x * 256;
    for (int i = idx; i < n16; i += stride) {
        const float* p = src + (size_t)i * 16;
        f32x4 a = *(const f32x4*)p;
        f32x4 b = *(const f32x4*)(p + 4);
        f32x4 c = *(const f32x4*)(p + 8);
        f32x4 d = *(const f32x4*)(p + 12);
        bf16x8 h0, h1;
#pragma unroll
        for (int j = 0; j < 4; ++j) {
            h0[j] = (bf16)a[j]; h0[4 + j] = (bf16)b[j];
            h1[j] = (bf16)c[j]; h1[4 + j] = (bf16)d[j];
        }
        bf16* q = dst + (size_t)i * 16;
        *(bf16x8*)q = h0;
        *(bf16x8*)(q + 8) = h1;
    }
}

// ---- high-reuse GEMM: C[M][N] = A[M][K]*B[N][K]^T + bias ----
// BM=256, BN=128, BK=32, 4 waves (256 thr), wave grid 2Mx2N -> per-wave output 128x64
// (reuse ratio Mw*Nw/(Mw+Nw)=42.7, m201-class -> LDS-BW limit ~62% MfmaUtil).
// Single LDS buffer (24KB), r6-verified loop: stage(global_load_lds w16) -> sync ->
// 12 ds_read_b128 + 32 MFMA -> sync. 2 blocks/CU (VGPR-bound) give inter-block overlap.
// Swizzle (rule #21 both-sides, 64B rows = 4 slots): phys slot p of row r holds logical
// slot p ^ ((r>>1)&3); staged via pre-swizzled global col; read at hi ^ ((lo>>1)&3).
// Bank check: lanes 0..7 cover all 8 16B-bank-columns, 8..15 repeat -> 2-way (free).
template <int OUT_BF16>
__global__ __launch_bounds__(256, 2) void gemm_w(
    const bf16* __restrict__ A, const bf16* __restrict__ B,
    const float* __restrict__ bias, void* __restrict__ Cout,
    int K, int ldc, int nbx)
{
    __shared__ bf16 As[256 * 32];
    __shared__ bf16 Bs[128 * 32];

    // bijective XCD-chunked swizzle (all our grids are %8==0)
    const int nwg = gridDim.x;
    const int cpx = nwg >> 3;
    const int swz = ((int)blockIdx.x & 7) * cpx + ((int)blockIdx.x >> 3);
    const int bx = swz % nbx, by = swz / nbx;
    const int brow = by * 256, bcol = bx * 128;

    const int tid  = threadIdx.x;
    const int wv   = tid >> 6, lane = tid & 63;
    const int lo   = lane & 15, hi = lane >> 4;
    const int wr   = wv >> 1, wc = wv & 1;      // 2x2 wave grid; per-wave 128 rows x 64 cols

    // staging: chunk = 16 rows x 32 elems (1KB); lane -> row l>>2, phys slot l&3
    const int srow = lane >> 2;                             // 0..15
    const int scol = ((lane & 3) ^ ((lane >> 3) & 3)) * 8;  // pre-swizzled global col (elems)

    f32x4 acc[8][4];
#pragma unroll
    for (int m = 0; m < 8; ++m)
#pragma unroll
        for (int n = 0; n < 4; ++n)
            acc[m][n] = (f32x4){0.f, 0.f, 0.f, 0.f};

    const int rslot = (hi ^ ((lo >> 1) & 3)) * 8;   // read slot offset (elems)

    for (int k0 = 0; k0 < K; k0 += 32) {
        // ---- stage: A 16 chunks (wave: 4w..4w+3), B 8 chunks (wave: 2w..2w+1) ----
#pragma unroll
        for (int i = 0; i < 4; ++i) {
            const int c = wv * 4 + i;
            GLOAD_LDS16(A + (size_t)(brow + c * 16 + srow) * K + k0 + scol, &As[c * 512]);
        }
#pragma unroll
        for (int i = 0; i < 2; ++i) {
            const int c = wv * 2 + i;
            GLOAD_LDS16(B + (size_t)(bcol + c * 16 + srow) * K + k0 + scol, &Bs[c * 512]);
        }
        __syncthreads();   // compiler drains vmcnt(0) here -> staged data visible

        bf16x8 af[8], bfr[4];
#pragma unroll
        for (int m = 0; m < 8; ++m)
            af[m] = *(const bf16x8*)&As[(wr * 128 + m * 16 + lo) * 32 + rslot];
#pragma unroll
        for (int n = 0; n < 4; ++n)
            bfr[n] = *(const bf16x8*)&Bs[(wc * 64 + n * 16 + lo) * 32 + rslot];

        __builtin_amdgcn_s_setprio(1);
#pragma unroll
        for (int m = 0; m < 8; ++m)
#pragma unroll
            for (int n = 0; n < 4; ++n)
                acc[m][n] = __builtin_amdgcn_mfma_f32_16x16x32_bf16(af[m], bfr[n], acc[m][n], 0, 0, 0);
        __builtin_amdgcn_s_setprio(0);

        __syncthreads();   // all reads done before next stage overwrites
    }

    // epilogue: C/D layout row=(lane>>4)*4+r, col=lane&15
#pragma unroll
    for (int m = 0; m < 8; ++m) {
        const int row = brow + wr * 128 + m * 16 + hi * 4;
#pragma unroll
        for (int n = 0; n < 4; ++n) {
            const int col = bcol + wc * 64 + n * 16 + lo;
            const float bv = bias[col];
#pragma unroll
            for (int r = 0; r < 4; ++r) {
                const float v = acc[m][n][r] + bv;
                if (OUT_BF16)
                    ((bf16*)Cout)[(size_t)(row + r) * ldc + col] = (bf16)v;
                else
                    ((float*)Cout)[(size_t)(row + r) * ldc + col] = v;
            }
        }
    }
}

// ---------------- MFMA flash attention: causal + ALiBi, bf16 in/out (r6/r7-verified) ----------------
__global__ __launch_bounds__(512) void attn_mfma(
    const bf16* __restrict__ qkv, bf16* __restrict__ attn_out)
{
    const int S = 2048, QKV = 12288, D = 4096, HD = 128;
    const int bid = blockIdx.x;
    const int h   = bid & 31;
    const int qi  = 15 - (bid >> 5);
    const int q0  = qi * 128;
    const int tid = threadIdx.x;
    const int w    = tid >> 6, lane = tid & 63;
    const int lo   = lane & 15, hi = lane >> 4;
    const int qbase = q0 + w * 16;

    __shared__ bf16 Ks[64 * 128];
    __shared__ bf16 Vs[128 * 72];
    __shared__ bf16 Ps[8 * 16 * 72];

    const float scale = 0.08838834764831845f;
    const float slope = exp2f(-0.25f * (float)(h + 1));

    bf16x8 qfrag[4];
#pragma unroll
    for (int ds = 0; ds < 4; ++ds)
        qfrag[ds] = *(const bf16x8*)(qkv + (size_t)(qbase + lo) * QKV + h * HD + ds * 32 + hi * 8);

    f32x4 o[8];
#pragma unroll
    for (int dt = 0; dt < 8; ++dt) o[dt] = (f32x4){0.f, 0.f, 0.f, 0.f};
    float mrow[4] = {-1e30f, -1e30f, -1e30f, -1e30f};
    float lrow[4] = {0.f, 0.f, 0.f, 0.f};

    const int krow = tid >> 3;
    const int kch  = tid & 7;
    const int vp2  = tid & 63;
    const int voct = tid >> 6;

    const int ntile = (q0 + 128) / 64;
    for (int t = 0; t < ntile; ++t) {
        const int kv0 = t * 64;
        {
            const bf16* kp = qkv + (size_t)(kv0 + krow) * QKV + D + h * HD + kch * 16;
            bf16x8 k0 = *(const bf16x8*)kp;
            bf16x8 k1 = *(const bf16x8*)(kp + 8);
            const int kb  = krow * 128 + kch * 16;
            const int swzk = (krow & 7) << 3;
            *(bf16x8*)&Ks[kb ^ swzk]       = k0;
            *(bf16x8*)&Ks[(kb + 8) ^ swzk] = k1;
        }
        {
            const bf16* vp = qkv + (size_t)(kv0 + voct * 8) * QKV + 2 * D + h * HD + 2 * vp2;
            bf16x8 r0, r1;
#pragma unroll
            for (int j = 0; j < 8; ++j) {
                const unsigned u = *(const unsigned*)(vp + (size_t)j * QKV);
                unsigned short us0 = (unsigned short)(u & 0xffff);
                unsigned short us1 = (unsigned short)(u >> 16);
                r0[j] = *(const bf16*)&us0;
                r1[j] = *(const bf16*)&us1;
            }
            *(bf16x8*)&Vs[(2 * vp2) * 72 + voct * 8]     = r0;
            *(bf16x8*)&Vs[(2 * vp2 + 1) * 72 + voct * 8] = r1;
        }
        __syncthreads();

        if (kv0 <= qbase + 15) {
            f32x4 c[4];
#pragma unroll
            for (int j = 0; j < 4; ++j) c[j] = (f32x4){0.f, 0.f, 0.f, 0.f};
            __builtin_amdgcn_s_setprio(1);
#pragma unroll
            for (int ds = 0; ds < 4; ++ds) {
#pragma unroll
                for (int j = 0; j < 4; ++j) {
                    const int r = j * 16 + lo;
                    bf16x8 b = *(const bf16x8*)&Ks[(r * 128 + ds * 32 + hi * 8) ^ ((r & 7) << 3)];
                    c[j] = __builtin_amdgcn_mfma_f32_16x16x32_bf16(qfrag[ds], b, c[j], 0, 0, 0);
                }
            }
            __builtin_amdgcn_s_setprio(0);
#pragma unroll
            for (int r = 0; r < 4; ++r) {
                const int q = qbase + hi * 4 + r;
                float s[4];
#pragma unroll
                for (int j = 0; j < 4; ++j) {
                    const int ki = kv0 + j * 16 + lo;
                    s[j] = c[j][r] * scale + slope * (float)(ki - (S - 1));
                    if (ki > q) s[j] = -1e30f;
                }
                float tm = fmaxf(fmaxf(s[0], s[1]), fmaxf(s[2], s[3]));
                tm = fmaxf(tm, __shfl_xor(tm, 1));
                tm = fmaxf(tm, __shfl_xor(tm, 2));
                tm = fmaxf(tm, __shfl_xor(tm, 4));
                tm = fmaxf(tm, __shfl_xor(tm, 8));
                const float mnew = fmaxf(mrow[r], tm);
                const float cr = __expf(mrow[r] - mnew);
                float p[4], ps = 0.f;
#pragma unroll
                for (int j = 0; j < 4; ++j) { p[j] = __expf(s[j] - mnew); ps += p[j]; }
                ps += __shfl_xor(ps, 1);
                ps += __shfl_xor(ps, 2);
                ps += __shfl_xor(ps, 4);
                ps += __shfl_xor(ps, 8);
                lrow[r] = lrow[r] * cr + ps;
                mrow[r] = mnew;
#pragma unroll
                for (int dt = 0; dt < 8; ++dt) o[dt][r] *= cr;
#pragma unroll
                for (int j = 0; j < 4; ++j)
                    Ps[w * 1152 + (hi * 4 + r) * 72 + j * 16 + lo] = (bf16)p[j];
            }
            bf16x8 pa0 = *(const bf16x8*)&Ps[w * 1152 + lo * 72 + hi * 8];
            bf16x8 pa1 = *(const bf16x8*)&Ps[w * 1152 + lo * 72 + 32 + hi * 8];
            __builtin_amdgcn_s_setprio(1);
#pragma unroll
            for (int dt = 0; dt < 8; ++dt) {
                bf16x8 bv0 = *(const bf16x8*)&Vs[(dt * 16 + lo) * 72 + hi * 8];
                bf16x8 bv1 = *(const bf16x8*)&Vs[(dt * 16 + lo) * 72 + 32 + hi * 8];
                o[dt] = __builtin_amdgcn_mfma_f32_16x16x32_bf16(pa0, bv0, o[dt], 0, 0, 0);
                o[dt] = __builtin_amdgcn_mfma_f32_16x16x32_bf16(pa1, bv1, o[dt], 0, 0, 0);
            }
            __builtin_amdgcn_s_setprio(0);
        }
        __syncthreads();
    }

#pragma unroll
    for (int r = 0; r < 4; ++r) {
        const float inv = 1.0f / lrow[r];
        const int q = qbase + hi * 4 + r;
        bf16* op = attn_out + (size_t)q * D + h * HD;
#pragma unroll
        for (int dt = 0; dt < 8; ++dt)
            op[dt * 16 + lo] = (bf16)(o[dt][r] * inv);
    }
}

extern "C" void kernel_launch(void* const* d_in, const int* in_sizes, int n_in,
                              void* d_out, int out_size, void* d_ws, size_t ws_size,
                              hipStream_t stream) {
    const int S = 2048, D = 4096, QKV = 12288;
    const int NH = 6144;
    const float* x     = (const float*)d_in[0];
    const float* w_qkv = (const float*)d_in[1];
    const float* b_qkv = (const float*)d_in[2];
    const float* w_out = (const float*)d_in[3];
    const float* b_out = (const float*)d_in[4];
    float* out = (float*)d_out;

    char* ws = (char*)d_ws;
    const size_t need_full = (size_t)S * D * 2 + (size_t)QKV * D * 2 + (size_t)S * QKV * 2;

    if (ws_size >= need_full) {
        // full-weight path: QKV 768 blocks; out-proj 256 blocks = 1 exact CU round
        bf16* xb    = (bf16*)ws;                                    // [2048][4096]
        bf16* attnb = xb;                                           // reuse after xb dead
        bf16* wqb   = (bf16*)(ws + (size_t)S * D * 2);              // [12288][4096]
        bf16* wob   = wqb;                                          // reuse after wqb dead
        bf16* qkvb  = (bf16*)(ws + (size_t)S * D * 2 + (size_t)QKV * D * 2);  // [2048][12288]

        cvt_f32_bf16<<<2048, 256, 0, stream>>>(x, xb, S * D / 16);
        cvt_f32_bf16<<<4096, 256, 0, stream>>>(w_qkv, wqb, QKV * D / 16);
        gemm_w<1><<<(QKV / 128) * (S / 256), 256, 0, stream>>>(xb, wqb, b_qkv, qkvb, D, QKV, QKV / 128);
        attn_mfma<<<512, 512, 0, stream>>>(qkvb, attnb);
        cvt_f32_bf16<<<2048, 256, 0, stream>>>(w_out, wob, D * D / 16);
        gemm_w<0><<<(D / 128) * (S / 256), 256, 0, stream>>>(attnb, wob, b_out, out, D, D, D / 128);
    } else {
        // halves path (peak 117.4 MB)
        bf16* xb    = (bf16*)ws;
        bf16* attnb = xb;
        bf16* wb    = (bf16*)(ws + (size_t)S * D * 2);              // [6144][4096]
        bf16* wob   = wb;
        bf16* qkvb  = (bf16*)(ws + (size_t)S * D * 2 + (size_t)NH * D * 2);

        cvt_f32_bf16<<<2048, 256, 0, stream>>>(x, xb, S * D / 16);
        cvt_f32_bf16<<<2048, 256, 0, stream>>>(w_qkv, wb, NH * D / 16);
        gemm_w<1><<<(NH / 128) * (S / 256), 256, 0, stream>>>(xb, wb, b_qkv, qkvb, D, QKV, NH / 128);
        cvt_f32_bf16<<<2048, 256, 0, stream>>>(w_qkv + (size_t)NH * D, wb, NH * D / 16);
        gemm_w<1><<<(NH / 128) * (S / 256), 256, 0, stream>>>(xb, wb, b_qkv + NH, qkvb + NH, D, QKV, NH / 128);
        attn_mfma<<<512, 512, 0, stream>>>(qkvb, attnb);
        cvt_f32_bf16<<<2048, 256, 0, stream>>>(w_out, wob, D * D / 16);
        gemm_w<0><<<(D / 128) * (S / 256), 256, 0, stream>>>(attnb, wob, b_out, out, D, D, D / 128);
    }
}

// Round 9
// 471.487 us; speedup vs baseline: 1.1619x; 1.1619x over previous
//
#include <hip/hip_runtime.h>
#include <hip/hip_bf16.h>

typedef __bf16 bf16;
typedef __attribute__((ext_vector_type(8))) __bf16 bf16x8;
typedef __attribute__((ext_vector_type(4))) float f32x4;

#define GLOAD_LDS16(g, l)                                                        \
    __builtin_amdgcn_global_load_lds(                                            \
        (const __attribute__((address_space(1))) void*)(g),                      \
        (__attribute__((address_space(3))) void*)(l), 16, 0, 0)

#define WAITV(n) asm volatile("s_waitcnt vmcnt(" #n ")" ::: "memory")
#define BAR()    __builtin_amdgcn_s_barrier()
#define SCHEDB() __builtin_amdgcn_sched_barrier(0)

// ---------------- fp32 -> bf16 conversion (vectorized, grid-stride) ----------------
__global__ __launch_bounds__(256) void cvt_f32_bf16(
    const float* __restrict__ src, bf16* __restrict__ dst, int n16)
{
    int idx = blockIdx.x * 256 + threadIdx.x;
    const int stride = gridDim.x * 256;
    for (int i = idx; i < n16; i += stride) {
        const float* p = src + (size_t)i * 16;
        f32x4 a = *(const f32x4*)p;
        f32x4 b = *(const f32x4*)(p + 4);
        f32x4 c = *(const f32x4*)(p + 8);
        f32x4 d = *(const f32x4*)(p + 12);
        bf16x8 h0, h1;
#pragma unroll
        for (int j = 0; j < 4; ++j) {
            h0[j] = (bf16)a[j]; h0[4 + j] = (bf16)b[j];
            h1[j] = (bf16)c[j]; h1[4 + j] = (bf16)d[j];
        }
        bf16* q = dst + (size_t)i * 16;
        *(bf16x8*)q = h0;
        *(bf16x8*)(q + 8) = h1;
    }
}

// ---- 4-phase pipelined GEMM (r7 schedule, un-serialized): C = A[M][K]*B[N][K]^T + bias ----
// BM=256, BN=128, BK=64, 8 waves. LDS 96KB: 2 bufs x {A0,A1,B}(128x64 each).
// Per phase: {8-12 ds_read || 1-2 stage-units} -> 16 MFMA (COMPILER-managed fine lgkmcnt,
// overlaps reads with MFMA) -> counted vmcnt(6) -> s_barrier. One barrier per phase:
// write-after-read hazards are guarded by the PREVIOUS phase's barrier (a wave passes it
// only after lgkm retired its reads), read-after-write by WAITV+BAR publication (r7-validated
// issue/wait table: ph1 A1[t+1]; ph2 A0,B[t+2]; ph3 A1[t+2]; ph4 A0,B[t+3]; steady vmcnt(6)).
// Swizzle (verified 0-conflict r6/r7): phys 16B-slot s of row r holds chunk s^(r&7).
template <int OUT_BF16>
__global__ __launch_bounds__(512, 2) void gemm_pipe(
    const bf16* __restrict__ A, const bf16* __restrict__ B,
    const float* __restrict__ bias, void* __restrict__ Cout,
    int K, int ldc, int nbx)
{
    __shared__ bf16 lds[2][384 * 64];   // per buf: A0 | A1 | B (each 128x64)

    const int nwg = gridDim.x;
    const int cpx = nwg >> 3;
    const int swz = ((int)blockIdx.x & 7) * cpx + ((int)blockIdx.x >> 3);
    const int bx = swz % nbx, by = swz / nbx;
    const int brow = by * 256, bcol = bx * 128;

    const int tid  = threadIdx.x;
    const int wv   = tid >> 6, lane = tid & 63;
    const int lo   = lane & 15, hi = lane >> 4;
    const int wrp  = wv >> 2, wcp = wv & 3;      // 2(M) x 4(N) wave grid over 128x128

    const int srow = lane >> 3;                       // row-in-chunk 0..7
    const int scol = ((lane & 7) ^ (lane >> 3)) * 8;  // pre-swizzled global col (elems)

    f32x4 accH0[4][2], accH1[4][2];
#pragma unroll
    for (int m = 0; m < 4; ++m)
#pragma unroll
        for (int n = 0; n < 2; ++n) {
            accH0[m][n] = (f32x4){0.f, 0.f, 0.f, 0.f};
            accH1[m][n] = (f32x4){0.f, 0.f, 0.f, 0.f};
        }

    auto STAGE = [&](int t, int unit) {   // unit: 0=A rows 0-127, 1=A rows 128-255, 2=B
        const int k0 = t * 64;
        bf16* lb = &lds[t & 1][unit * (128 * 64)];
        const bf16* gb = (unit == 2) ? (B + (size_t)bcol * K + k0)
                                     : (A + (size_t)(brow + unit * 128) * K + k0);
#pragma unroll
        for (int j = 0; j < 2; ++j) {
            const int c = wv * 2 + j;
            GLOAD_LDS16(gb + (size_t)(c * 8 + srow) * K + scol, lb + c * 512);
        }
    };

    bf16x8 af[4][2], bfr[2][2];
    auto LOADB = [&](int b) {
#pragma unroll
        for (int n = 0; n < 2; ++n) {
            const int rb = wcp * 32 + n * 16 + lo;
#pragma unroll
            for (int kk = 0; kk < 2; ++kk)
                bfr[n][kk] = *(const bf16x8*)&lds[b][256 * 64 + rb * 64 + (((kk * 4 + hi) ^ (lo & 7)) * 8)];
        }
    };
    auto LOADA = [&](int b, int half) {
#pragma unroll
        for (int m = 0; m < 4; ++m) {
            const int ru = wrp * 64 + m * 16 + lo;
#pragma unroll
            for (int kk = 0; kk < 2; ++kk)
                af[m][kk] = *(const bf16x8*)&lds[b][half * (128 * 64) + ru * 64 + (((kk * 4 + hi) ^ (lo & 7)) * 8)];
        }
    };
    auto MFMA16 = [&](f32x4 (&acc)[4][2]) {
        __builtin_amdgcn_s_setprio(1);
#pragma unroll
        for (int m = 0; m < 4; ++m)
#pragma unroll
            for (int n = 0; n < 2; ++n)
#pragma unroll
                for (int kk = 0; kk < 2; ++kk)
                    acc[m][n] = __builtin_amdgcn_mfma_f32_16x16x32_bf16(af[m][kk], bfr[n][kk], acc[m][n], 0, 0, 0);
        __builtin_amdgcn_s_setprio(0);
    };

    const int nt = K / 64, niter = nt / 2;

    // prologue: A0[0],B[0],A1[0],A0[1],B[1]; vmcnt(6) retires A0[0],B[0]
    STAGE(0, 0); STAGE(0, 2); STAGE(0, 1); STAGE(1, 0); STAGE(1, 2);
    WAITV(6); BAR(); SCHEDB();

    for (int it = 0; it < niter; ++it) {
        const int t0 = 2 * it;
        const bool nl = (it + 1 < niter);

        // ---- phase 1: tile t0 (buf0), rows 0-127 ----
        LOADB(0); LOADA(0, 0);
        STAGE(t0 + 1, 1);
        MFMA16(accH0);                       // compiler overlaps lgkm waits with MFMA
        WAITV(6); BAR(); SCHEDB();           // confirm A1[t0]

        // ---- phase 2: tile t0, rows 128-255 ----
        LOADA(0, 1);
        if (nl) { STAGE(t0 + 2, 0); STAGE(t0 + 2, 2); }
        MFMA16(accH1);
        if (nl) WAITV(6); else WAITV(2);     // confirm A0,B[t0+1]
        BAR(); SCHEDB();

        // ---- phase 3: tile t0+1 (buf1), rows 0-127 ----
        LOADB(1); LOADA(1, 0);
        if (nl) STAGE(t0 + 2, 1);
        MFMA16(accH0);
        if (nl) WAITV(6); else WAITV(0);     // confirm A1[t0+1]
        BAR(); SCHEDB();

        // ---- phase 4: tile t0+1, rows 128-255 ----
        LOADA(1, 1);
        if (nl) { STAGE(t0 + 3, 0); STAGE(t0 + 3, 2); }
        MFMA16(accH1);
        if (nl) { WAITV(6); BAR(); SCHEDB(); }   // confirm A0,B[t0+2]
    }

    // epilogue: C/D layout row=(lane>>4)*4+r, col=lane&15
    auto EPI = [&](f32x4 (&acc)[4][2], int half) {
#pragma unroll
        for (int m = 0; m < 4; ++m) {
            const int row = brow + half * 128 + wrp * 64 + m * 16 + hi * 4;
#pragma unroll
            for (int n = 0; n < 2; ++n) {
                const int col = bcol + wcp * 32 + n * 16 + lo;
                const float bv = bias[col];
#pragma unroll
                for (int r = 0; r < 4; ++r) {
                    const float v = acc[m][n][r] + bv;
                    if (OUT_BF16)
                        ((bf16*)Cout)[(size_t)(row + r) * ldc + col] = (bf16)v;
                    else
                        ((float*)Cout)[(size_t)(row + r) * ldc + col] = v;
                }
            }
        }
    };
    EPI(accH0, 0);
    EPI(accH1, 1);
}

// ---------------- MFMA flash attention: causal + ALiBi, bf16 in/out (r6-verified) + T13 ----------------
__global__ __launch_bounds__(512) void attn_mfma(
    const bf16* __restrict__ qkv, bf16* __restrict__ attn_out)
{
    const int S = 2048, QKV = 12288, D = 4096, HD = 128;
    const int bid = blockIdx.x;
    const int h   = bid & 31;
    const int qi  = 15 - (bid >> 5);
    const int q0  = qi * 128;
    const int tid = threadIdx.x;
    const int w    = tid >> 6, lane = tid & 63;
    const int lo   = lane & 15, hi = lane >> 4;
    const int qbase = q0 + w * 16;

    __shared__ bf16 Ks[64 * 128];
    __shared__ bf16 Vs[128 * 72];
    __shared__ bf16 Ps[8 * 16 * 72];

    const float scale = 0.08838834764831845f;
    const float slope = exp2f(-0.25f * (float)(h + 1));

    bf16x8 qfrag[4];
#pragma unroll
    for (int ds = 0; ds < 4; ++ds)
        qfrag[ds] = *(const bf16x8*)(qkv + (size_t)(qbase + lo) * QKV + h * HD + ds * 32 + hi * 8);

    f32x4 o[8];
#pragma unroll
    for (int dt = 0; dt < 8; ++dt) o[dt] = (f32x4){0.f, 0.f, 0.f, 0.f};
    float mrow[4] = {-1e30f, -1e30f, -1e30f, -1e30f};
    float lrow[4] = {0.f, 0.f, 0.f, 0.f};

    const int krow = tid >> 3;
    const int kch  = tid & 7;
    const int vp2  = tid & 63;
    const int voct = tid >> 6;

    const int ntile = (q0 + 128) / 64;
    for (int t = 0; t < ntile; ++t) {
        const int kv0 = t * 64;
        {
            const bf16* kp = qkv + (size_t)(kv0 + krow) * QKV + D + h * HD + kch * 16;
            bf16x8 k0 = *(const bf16x8*)kp;
            bf16x8 k1 = *(const bf16x8*)(kp + 8);
            const int kb  = krow * 128 + kch * 16;
            const int swzk = (krow & 7) << 3;
            *(bf16x8*)&Ks[kb ^ swzk]       = k0;
            *(bf16x8*)&Ks[(kb + 8) ^ swzk] = k1;
        }
        {
            const bf16* vp = qkv + (size_t)(kv0 + voct * 8) * QKV + 2 * D + h * HD + 2 * vp2;
            bf16x8 r0, r1;
#pragma unroll
            for (int j = 0; j < 8; ++j) {
                const unsigned u = *(const unsigned*)(vp + (size_t)j * QKV);
                unsigned short us0 = (unsigned short)(u & 0xffff);
                unsigned short us1 = (unsigned short)(u >> 16);
                r0[j] = *(const bf16*)&us0;
                r1[j] = *(const bf16*)&us1;
            }
            *(bf16x8*)&Vs[(2 * vp2) * 72 + voct * 8]     = r0;
            *(bf16x8*)&Vs[(2 * vp2 + 1) * 72 + voct * 8] = r1;
        }
        __syncthreads();

        if (kv0 <= qbase + 15) {
            f32x4 c[4];
#pragma unroll
            for (int j = 0; j < 4; ++j) c[j] = (f32x4){0.f, 0.f, 0.f, 0.f};
            __builtin_amdgcn_s_setprio(1);
#pragma unroll
            for (int ds = 0; ds < 4; ++ds) {
#pragma unroll
                for (int j = 0; j < 4; ++j) {
                    const int r = j * 16 + lo;
                    bf16x8 b = *(const bf16x8*)&Ks[(r * 128 + ds * 32 + hi * 8) ^ ((r & 7) << 3)];
                    c[j] = __builtin_amdgcn_mfma_f32_16x16x32_bf16(qfrag[ds], b, c[j], 0, 0, 0);
                }
            }
            __builtin_amdgcn_s_setprio(0);
#pragma unroll
            for (int r = 0; r < 4; ++r) {
                const int q = qbase + hi * 4 + r;
                float s[4];
#pragma unroll
                for (int j = 0; j < 4; ++j) {
                    const int ki = kv0 + j * 16 + lo;
                    s[j] = c[j][r] * scale + slope * (float)(ki - (S - 1));
                    if (ki > q) s[j] = -1e30f;
                }
                float tm = fmaxf(fmaxf(s[0], s[1]), fmaxf(s[2], s[3]));
                tm = fmaxf(tm, __shfl_xor(tm, 1));
                tm = fmaxf(tm, __shfl_xor(tm, 2));
                tm = fmaxf(tm, __shfl_xor(tm, 4));
                tm = fmaxf(tm, __shfl_xor(tm, 8));
                // T13 defer-max: rescale only when max grew by > 8 (P bounded by e^8, bf16-safe)
                if (tm > mrow[r] + 8.0f) {
                    const float cr = __expf(mrow[r] - tm);
                    mrow[r] = tm;
                    lrow[r] *= cr;
#pragma unroll
                    for (int dt = 0; dt < 8; ++dt) o[dt][r] *= cr;
                }
                float p[4], ps = 0.f;
#pragma unroll
                for (int j = 0; j < 4; ++j) { p[j] = __expf(s[j] - mrow[r]); ps += p[j]; }
                ps += __shfl_xor(ps, 1);
                ps += __shfl_xor(ps, 2);
                ps += __shfl_xor(ps, 4);
                ps += __shfl_xor(ps, 8);
                lrow[r] += ps;
#pragma unroll
                for (int j = 0; j < 4; ++j)
                    Ps[w * 1152 + (hi * 4 + r) * 72 + j * 16 + lo] = (bf16)p[j];
            }
            bf16x8 pa0 = *(const bf16x8*)&Ps[w * 1152 + lo * 72 + hi * 8];
            bf16x8 pa1 = *(const bf16x8*)&Ps[w * 1152 + lo * 72 + 32 + hi * 8];
            __builtin_amdgcn_s_setprio(1);
#pragma unroll
            for (int dt = 0; dt < 8; ++dt) {
                bf16x8 bv0 = *(const bf16x8*)&Vs[(dt * 16 + lo) * 72 + hi * 8];
                bf16x8 bv1 = *(const bf16x8*)&Vs[(dt * 16 + lo) * 72 + 32 + hi * 8];
                o[dt] = __builtin_amdgcn_mfma_f32_16x16x32_bf16(pa0, bv0, o[dt], 0, 0, 0);
                o[dt] = __builtin_amdgcn_mfma_f32_16x16x32_bf16(pa1, bv1, o[dt], 0, 0, 0);
            }
            __builtin_amdgcn_s_setprio(0);
        }
        __syncthreads();
    }

#pragma unroll
    for (int r = 0; r < 4; ++r) {
        const float inv = 1.0f / lrow[r];
        const int q = qbase + hi * 4 + r;
        bf16* op = attn_out + (size_t)q * D + h * HD;
#pragma unroll
        for (int dt = 0; dt < 8; ++dt)
            op[dt * 16 + lo] = (bf16)(o[dt][r] * inv);
    }
}

extern "C" void kernel_launch(void* const* d_in, const int* in_sizes, int n_in,
                              void* d_out, int out_size, void* d_ws, size_t ws_size,
                              hipStream_t stream) {
    const int S = 2048, D = 4096, QKV = 12288;
    const int NH = 6144;
    const float* x     = (const float*)d_in[0];
    const float* w_qkv = (const float*)d_in[1];
    const float* b_qkv = (const float*)d_in[2];
    const float* w_out = (const float*)d_in[3];
    const float* b_out = (const float*)d_in[4];
    float* out = (float*)d_out;

    char* ws = (char*)d_ws;
    const size_t need_full = (size_t)S * D * 2 + (size_t)QKV * D * 2 + (size_t)S * QKV * 2;

    if (ws_size >= need_full) {
        bf16* xb    = (bf16*)ws;                                    // [2048][4096]
        bf16* attnb = xb;                                           // reuse after xb dead
        bf16* wqb   = (bf16*)(ws + (size_t)S * D * 2);              // [12288][4096]
        bf16* wob   = wqb;                                          // reuse after wqb dead
        bf16* qkvb  = (bf16*)(ws + (size_t)S * D * 2 + (size_t)QKV * D * 2);  // [2048][12288]

        cvt_f32_bf16<<<2048, 256, 0, stream>>>(x, xb, S * D / 16);
        cvt_f32_bf16<<<4096, 256, 0, stream>>>(w_qkv, wqb, QKV * D / 16);
        gemm_pipe<1><<<(QKV / 128) * (S / 256), 512, 0, stream>>>(xb, wqb, b_qkv, qkvb, D, QKV, QKV / 128);
        attn_mfma<<<512, 512, 0, stream>>>(qkvb, attnb);
        cvt_f32_bf16<<<2048, 256, 0, stream>>>(w_out, wob, D * D / 16);
        gemm_pipe<0><<<(D / 128) * (S / 256), 512, 0, stream>>>(attnb, wob, b_out, out, D, D, D / 128);
    } else {
        bf16* xb    = (bf16*)ws;
        bf16* attnb = xb;
        bf16* wb    = (bf16*)(ws + (size_t)S * D * 2);              // [6144][4096]
        bf16* wob   = wb;
        bf16* qkvb  = (bf16*)(ws + (size_t)S * D * 2 + (size_t)NH * D * 2);

        cvt_f32_bf16<<<2048, 256, 0, stream>>>(x, xb, S * D / 16);
        cvt_f32_bf16<<<2048, 256, 0, stream>>>(w_qkv, wb, NH * D / 16);
        gemm_pipe<1><<<(NH / 128) * (S / 256), 512, 0, stream>>>(xb, wb, b_qkv, qkvb, D, QKV, NH / 128);
        cvt_f32_bf16<<<2048, 256, 0, stream>>>(w_qkv + (size_t)NH * D, wb, NH * D / 16);
        gemm_pipe<1><<<(NH / 128) * (S / 256), 512, 0, stream>>>(xb, wb, b_qkv + NH, qkvb + NH, D, QKV, NH / 128);
        attn_mfma<<<512, 512, 0, stream>>>(qkvb, attnb);
        cvt_f32_bf16<<<2048, 256, 0, stream>>>(w_out, wob, D * D / 16);
        gemm_pipe<0><<<(D / 128) * (S / 256), 512, 0, stream>>>(attnb, wob, b_out, out, D, D, D / 128);
    }
}

// Round 10
// 438.380 us; speedup vs baseline: 1.2496x; 1.0755x over previous
//
#include <hip/hip_runtime.h>
#include <hip/hip_bf16.h>

typedef __bf16 bf16;
typedef __attribute__((ext_vector_type(8))) __bf16 bf16x8;
typedef __attribute__((ext_vector_type(4))) float f32x4;

#define GLOAD_LDS16(g, l)                                                        \
    __builtin_amdgcn_global_load_lds(                                            \
        (const __attribute__((address_space(1))) void*)(g),                      \
        (__attribute__((address_space(3))) void*)(l), 16, 0, 0)

#define WAITV(n) asm volatile("s_waitcnt vmcnt(" #n ")" ::: "memory")
#define BAR()    __builtin_amdgcn_s_barrier()
#define SCHEDB() __builtin_amdgcn_sched_barrier(0)

// ---------------- fp32 -> bf16 conversion (vectorized, grid-stride) ----------------
__global__ __launch_bounds__(256) void cvt_f32_bf16(
    const float* __restrict__ src, bf16* __restrict__ dst, int n16)
{
    int idx = blockIdx.x * 256 + threadIdx.x;
    const int stride = gridDim.x * 256;
    for (int i = idx; i < n16; i += stride) {
        const float* p = src + (size_t)i * 16;
        f32x4 a = *(const f32x4*)p;
        f32x4 b = *(const f32x4*)(p + 4);
        f32x4 c = *(const f32x4*)(p + 8);
        f32x4 d = *(const f32x4*)(p + 12);
        bf16x8 h0, h1;
#pragma unroll
        for (int j = 0; j < 4; ++j) {
            h0[j] = (bf16)a[j]; h0[4 + j] = (bf16)b[j];
            h1[j] = (bf16)c[j]; h1[4 + j] = (bf16)d[j];
        }
        bf16* q = dst + (size_t)i * 16;
        *(bf16x8*)q = h0;
        *(bf16x8*)(q + 8) = h1;
    }
}

// ---- 4-phase pipelined GEMM (r9 schedule) + locality-window block map ----
// BM=256, BN=128, BK=64, 8 waves, LDS 96KB (1 block/CU). Schedule r9-verified.
// Block map: each 256-block window covers 32 bx (weight panels) x all 8 by; XCD (bid&7)
// owns 4 consecutive bx x 8 by -> weight panel fetched once/window, L2/L3-served;
// A row-panels (16.8MB) L3-resident across windows. Bijective for grid = nbx*8, nbx%32==0.
template <int OUT_BF16>
__global__ __launch_bounds__(512, 2) void gemm_pipe(
    const bf16* __restrict__ A, const bf16* __restrict__ B,
    const float* __restrict__ bias, void* __restrict__ Cout,
    int K, int ldc, int nbx)
{
    __shared__ bf16 lds[2][384 * 64];   // per buf: A0 | A1 | B (each 128x64)

    int bx, by;
    if ((nbx & 31) == 0) {
        const int r = (int)blockIdx.x & 255;
        const int slot = r >> 3;                       // 0..31
        bx = ((int)blockIdx.x >> 8) * 32 + (r & 7) * 4 + (slot >> 3);
        by = slot & 7;
    } else {                                           // fallback: XCD-chunked swizzle
        const int cpx = gridDim.x >> 3;
        const int swz = ((int)blockIdx.x & 7) * cpx + ((int)blockIdx.x >> 3);
        bx = swz % nbx; by = swz / nbx;
    }
    const int brow = by * 256, bcol = bx * 128;

    const int tid  = threadIdx.x;
    const int wv   = tid >> 6, lane = tid & 63;
    const int lo   = lane & 15, hi = lane >> 4;
    const int wrp  = wv >> 2, wcp = wv & 3;      // 2(M) x 4(N) wave grid over 128x128

    const int srow = lane >> 3;                       // row-in-chunk 0..7
    const int scol = ((lane & 7) ^ (lane >> 3)) * 8;  // pre-swizzled global col (elems)

    f32x4 accH0[4][2], accH1[4][2];
#pragma unroll
    for (int m = 0; m < 4; ++m)
#pragma unroll
        for (int n = 0; n < 2; ++n) {
            accH0[m][n] = (f32x4){0.f, 0.f, 0.f, 0.f};
            accH1[m][n] = (f32x4){0.f, 0.f, 0.f, 0.f};
        }

    auto STAGE = [&](int t, int unit) {   // unit: 0=A rows 0-127, 1=A rows 128-255, 2=B
        const int k0 = t * 64;
        bf16* lb = &lds[t & 1][unit * (128 * 64)];
        const bf16* gb = (unit == 2) ? (B + (size_t)bcol * K + k0)
                                     : (A + (size_t)(brow + unit * 128) * K + k0);
#pragma unroll
        for (int j = 0; j < 2; ++j) {
            const int c = wv * 2 + j;
            GLOAD_LDS16(gb + (size_t)(c * 8 + srow) * K + scol, lb + c * 512);
        }
    };

    bf16x8 af[4][2], bfr[2][2];
    auto LOADB = [&](int b) {
#pragma unroll
        for (int n = 0; n < 2; ++n) {
            const int rb = wcp * 32 + n * 16 + lo;
#pragma unroll
            for (int kk = 0; kk < 2; ++kk)
                bfr[n][kk] = *(const bf16x8*)&lds[b][256 * 64 + rb * 64 + (((kk * 4 + hi) ^ (lo & 7)) * 8)];
        }
    };
    auto LOADA = [&](int b, int half) {
#pragma unroll
        for (int m = 0; m < 4; ++m) {
            const int ru = wrp * 64 + m * 16 + lo;
#pragma unroll
            for (int kk = 0; kk < 2; ++kk)
                af[m][kk] = *(const bf16x8*)&lds[b][half * (128 * 64) + ru * 64 + (((kk * 4 + hi) ^ (lo & 7)) * 8)];
        }
    };
    auto MFMA16 = [&](f32x4 (&acc)[4][2]) {
        __builtin_amdgcn_s_setprio(1);
#pragma unroll
        for (int m = 0; m < 4; ++m)
#pragma unroll
            for (int n = 0; n < 2; ++n)
#pragma unroll
                for (int kk = 0; kk < 2; ++kk)
                    acc[m][n] = __builtin_amdgcn_mfma_f32_16x16x32_bf16(af[m][kk], bfr[n][kk], acc[m][n], 0, 0, 0);
        __builtin_amdgcn_s_setprio(0);
    };

    const int nt = K / 64, niter = nt / 2;

    // prologue: A0[0],B[0],A1[0],A0[1],B[1]; vmcnt(6) retires A0[0],B[0]
    STAGE(0, 0); STAGE(0, 2); STAGE(0, 1); STAGE(1, 0); STAGE(1, 2);
    WAITV(6); BAR(); SCHEDB();

    for (int it = 0; it < niter; ++it) {
        const int t0 = 2 * it;
        const bool nl = (it + 1 < niter);

        // ---- phase 1: tile t0 (buf0), rows 0-127 ----
        LOADB(0); LOADA(0, 0);
        STAGE(t0 + 1, 1);
        MFMA16(accH0);                       // compiler-managed fine lgkmcnt overlap
        WAITV(6); BAR(); SCHEDB();           // confirm A1[t0]

        // ---- phase 2: tile t0, rows 128-255 ----
        LOADA(0, 1);
        if (nl) { STAGE(t0 + 2, 0); STAGE(t0 + 2, 2); }
        MFMA16(accH1);
        if (nl) WAITV(6); else WAITV(2);     // confirm A0,B[t0+1]
        BAR(); SCHEDB();

        // ---- phase 3: tile t0+1 (buf1), rows 0-127 ----
        LOADB(1); LOADA(1, 0);
        if (nl) STAGE(t0 + 2, 1);
        MFMA16(accH0);
        if (nl) WAITV(6); else WAITV(0);     // confirm A1[t0+1]
        BAR(); SCHEDB();

        // ---- phase 4: tile t0+1, rows 128-255 ----
        LOADA(1, 1);
        if (nl) { STAGE(t0 + 3, 0); STAGE(t0 + 3, 2); }
        MFMA16(accH1);
        if (nl) { WAITV(6); BAR(); SCHEDB(); }   // confirm A0,B[t0+2]
    }

    // epilogue: C/D layout row=(lane>>4)*4+r, col=lane&15
    auto EPI = [&](f32x4 (&acc)[4][2], int half) {
#pragma unroll
        for (int m = 0; m < 4; ++m) {
            const int row = brow + half * 128 + wrp * 64 + m * 16 + hi * 4;
#pragma unroll
            for (int n = 0; n < 2; ++n) {
                const int col = bcol + wcp * 32 + n * 16 + lo;
                const float bv = bias[col];
#pragma unroll
                for (int r = 0; r < 4; ++r) {
                    const float v = acc[m][n][r] + bv;
                    if (OUT_BF16)
                        ((bf16*)Cout)[(size_t)(row + r) * ldc + col] = (bf16)v;
                    else
                        ((float*)Cout)[(size_t)(row + r) * ldc + col] = v;
                }
            }
        }
    };
    EPI(accH0, 0);
    EPI(accH1, 1);
}

// ---------------- MFMA flash attention: causal + ALiBi, bf16 in/out (r6-verified, T13 reverted) ----------------
__global__ __launch_bounds__(512) void attn_mfma(
    const bf16* __restrict__ qkv, bf16* __restrict__ attn_out)
{
    const int S = 2048, QKV = 12288, D = 4096, HD = 128;
    const int bid = blockIdx.x;
    const int h   = bid & 31;
    const int qi  = 15 - (bid >> 5);
    const int q0  = qi * 128;
    const int tid = threadIdx.x;
    const int w    = tid >> 6, lane = tid & 63;
    const int lo   = lane & 15, hi = lane >> 4;
    const int qbase = q0 + w * 16;

    __shared__ bf16 Ks[64 * 128];
    __shared__ bf16 Vs[128 * 72];
    __shared__ bf16 Ps[8 * 16 * 72];

    const float scale = 0.08838834764831845f;
    const float slope = exp2f(-0.25f * (float)(h + 1));

    bf16x8 qfrag[4];
#pragma unroll
    for (int ds = 0; ds < 4; ++ds)
        qfrag[ds] = *(const bf16x8*)(qkv + (size_t)(qbase + lo) * QKV + h * HD + ds * 32 + hi * 8);

    f32x4 o[8];
#pragma unroll
    for (int dt = 0; dt < 8; ++dt) o[dt] = (f32x4){0.f, 0.f, 0.f, 0.f};
    float mrow[4] = {-1e30f, -1e30f, -1e30f, -1e30f};
    float lrow[4] = {0.f, 0.f, 0.f, 0.f};

    const int krow = tid >> 3;
    const int kch  = tid & 7;
    const int vp2  = tid & 63;
    const int voct = tid >> 6;

    const int ntile = (q0 + 128) / 64;
    for (int t = 0; t < ntile; ++t) {
        const int kv0 = t * 64;
        {
            const bf16* kp = qkv + (size_t)(kv0 + krow) * QKV + D + h * HD + kch * 16;
            bf16x8 k0 = *(const bf16x8*)kp;
            bf16x8 k1 = *(const bf16x8*)(kp + 8);
            const int kb  = krow * 128 + kch * 16;
            const int swzk = (krow & 7) << 3;
            *(bf16x8*)&Ks[kb ^ swzk]       = k0;
            *(bf16x8*)&Ks[(kb + 8) ^ swzk] = k1;
        }
        {
            const bf16* vp = qkv + (size_t)(kv0 + voct * 8) * QKV + 2 * D + h * HD + 2 * vp2;
            bf16x8 r0, r1;
#pragma unroll
            for (int j = 0; j < 8; ++j) {
                const unsigned u = *(const unsigned*)(vp + (size_t)j * QKV);
                unsigned short us0 = (unsigned short)(u & 0xffff);
                unsigned short us1 = (unsigned short)(u >> 16);
                r0[j] = *(const bf16*)&us0;
                r1[j] = *(const bf16*)&us1;
            }
            *(bf16x8*)&Vs[(2 * vp2) * 72 + voct * 8]     = r0;
            *(bf16x8*)&Vs[(2 * vp2 + 1) * 72 + voct * 8] = r1;
        }
        __syncthreads();

        if (kv0 <= qbase + 15) {
            f32x4 c[4];
#pragma unroll
            for (int j = 0; j < 4; ++j) c[j] = (f32x4){0.f, 0.f, 0.f, 0.f};
            __builtin_amdgcn_s_setprio(1);
#pragma unroll
            for (int ds = 0; ds < 4; ++ds) {
#pragma unroll
                for (int j = 0; j < 4; ++j) {
                    const int r = j * 16 + lo;
                    bf16x8 b = *(const bf16x8*)&Ks[(r * 128 + ds * 32 + hi * 8) ^ ((r & 7) << 3)];
                    c[j] = __builtin_amdgcn_mfma_f32_16x16x32_bf16(qfrag[ds], b, c[j], 0, 0, 0);
                }
            }
            __builtin_amdgcn_s_setprio(0);
#pragma unroll
            for (int r = 0; r < 4; ++r) {
                const int q = qbase + hi * 4 + r;
                float s[4];
#pragma unroll
                for (int j = 0; j < 4; ++j) {
                    const int ki = kv0 + j * 16 + lo;
                    s[j] = c[j][r] * scale + slope * (float)(ki - (S - 1));
                    if (ki > q) s[j] = -1e30f;
                }
                float tm = fmaxf(fmaxf(s[0], s[1]), fmaxf(s[2], s[3]));
                tm = fmaxf(tm, __shfl_xor(tm, 1));
                tm = fmaxf(tm, __shfl_xor(tm, 2));
                tm = fmaxf(tm, __shfl_xor(tm, 4));
                tm = fmaxf(tm, __shfl_xor(tm, 8));
                const float mnew = fmaxf(mrow[r], tm);
                const float cr = __expf(mrow[r] - mnew);
                float p[4], ps = 0.f;
#pragma unroll
                for (int j = 0; j < 4; ++j) { p[j] = __expf(s[j] - mnew); ps += p[j]; }
                ps += __shfl_xor(ps, 1);
                ps += __shfl_xor(ps, 2);
                ps += __shfl_xor(ps, 4);
                ps += __shfl_xor(ps, 8);
                lrow[r] = lrow[r] * cr + ps;
                mrow[r] = mnew;
#pragma unroll
                for (int dt = 0; dt < 8; ++dt) o[dt][r] *= cr;
#pragma unroll
                for (int j = 0; j < 4; ++j)
                    Ps[w * 1152 + (hi * 4 + r) * 72 + j * 16 + lo] = (bf16)p[j];
            }
            bf16x8 pa0 = *(const bf16x8*)&Ps[w * 1152 + lo * 72 + hi * 8];
            bf16x8 pa1 = *(const bf16x8*)&Ps[w * 1152 + lo * 72 + 32 + hi * 8];
            __builtin_amdgcn_s_setprio(1);
#pragma unroll
            for (int dt = 0; dt < 8; ++dt) {
                bf16x8 bv0 = *(const bf16x8*)&Vs[(dt * 16 + lo) * 72 + hi * 8];
                bf16x8 bv1 = *(const bf16x8*)&Vs[(dt * 16 + lo) * 72 + 32 + hi * 8];
                o[dt] = __builtin_amdgcn_mfma_f32_16x16x32_bf16(pa0, bv0, o[dt], 0, 0, 0);
                o[dt] = __builtin_amdgcn_mfma_f32_16x16x32_bf16(pa1, bv1, o[dt], 0, 0, 0);
            }
            __builtin_amdgcn_s_setprio(0);
        }
        __syncthreads();
    }

#pragma unroll
    for (int r = 0; r < 4; ++r) {
        const float inv = 1.0f / lrow[r];
        const int q = qbase + hi * 4 + r;
        bf16* op = attn_out + (size_t)q * D + h * HD;
#pragma unroll
        for (int dt = 0; dt < 8; ++dt)
            op[dt * 16 + lo] = (bf16)(o[dt][r] * inv);
    }
}

extern "C" void kernel_launch(void* const* d_in, const int* in_sizes, int n_in,
                              void* d_out, int out_size, void* d_ws, size_t ws_size,
                              hipStream_t stream) {
    const int S = 2048, D = 4096, QKV = 12288;
    const int NH = 6144;
    const float* x     = (const float*)d_in[0];
    const float* w_qkv = (const float*)d_in[1];
    const float* b_qkv = (const float*)d_in[2];
    const float* w_out = (const float*)d_in[3];
    const float* b_out = (const float*)d_in[4];
    float* out = (float*)d_out;

    char* ws = (char*)d_ws;
    const size_t need_full = (size_t)S * D * 2 + (size_t)QKV * D * 2 + (size_t)S * QKV * 2;

    if (ws_size >= need_full) {
        bf16* xb    = (bf16*)ws;                                    // [2048][4096]
        bf16* attnb = xb;                                           // reuse after xb dead
        bf16* wqb   = (bf16*)(ws + (size_t)S * D * 2);              // [12288][4096]
        bf16* wob   = wqb;                                          // reuse after wqb dead
        bf16* qkvb  = (bf16*)(ws + (size_t)S * D * 2 + (size_t)QKV * D * 2);  // [2048][12288]

        cvt_f32_bf16<<<2048, 256, 0, stream>>>(x, xb, S * D / 16);
        cvt_f32_bf16<<<4096, 256, 0, stream>>>(w_qkv, wqb, QKV * D / 16);
        gemm_pipe<1><<<(QKV / 128) * (S / 256), 512, 0, stream>>>(xb, wqb, b_qkv, qkvb, D, QKV, QKV / 128);
        attn_mfma<<<512, 512, 0, stream>>>(qkvb, attnb);
        cvt_f32_bf16<<<2048, 256, 0, stream>>>(w_out, wob, D * D / 16);
        gemm_pipe<0><<<(D / 128) * (S / 256), 512, 0, stream>>>(attnb, wob, b_out, out, D, D, D / 128);
    } else {
        bf16* xb    = (bf16*)ws;
        bf16* attnb = xb;
        bf16* wb    = (bf16*)(ws + (size_t)S * D * 2);              // [6144][4096]
        bf16* wob   = wb;
        bf16* qkvb  = (bf16*)(ws + (size_t)S * D * 2 + (size_t)NH * D * 2);

        cvt_f32_bf16<<<2048, 256, 0, stream>>>(x, xb, S * D / 16);
        cvt_f32_bf16<<<2048, 256, 0, stream>>>(w_qkv, wb, NH * D / 16);
        gemm_pipe<1><<<(NH / 128) * (S / 256), 512, 0, stream>>>(xb, wb, b_qkv, qkvb, D, QKV, NH / 128);
        cvt_f32_bf16<<<2048, 256, 0, stream>>>(w_qkv + (size_t)NH * D, wb, NH * D / 16);
        gemm_pipe<1><<<(NH / 128) * (S / 256), 512, 0, stream>>>(xb, wb, b_qkv + NH, qkvb + NH, D, QKV, NH / 128);
        attn_mfma<<<512, 512, 0, stream>>>(qkvb, attnb);
        cvt_f32_bf16<<<2048, 256, 0, stream>>>(w_out, wob, D * D / 16);
        gemm_pipe<0><<<(D / 128) * (S / 256), 512, 0, stream>>>(attnb, wob, b_out, out, D, D, D / 128);
    }
}

// Round 11
// 435.028 us; speedup vs baseline: 1.2593x; 1.0077x over previous
//
#include <hip/hip_runtime.h>
#include <hip/hip_bf16.h>

typedef __bf16 bf16;
typedef __attribute__((ext_vector_type(8))) __bf16 bf16x8;
typedef __attribute__((ext_vector_type(4))) float f32x4;

#define GLOAD_LDS16(g, l)                                                        \
    __builtin_amdgcn_global_load_lds(                                            \
        (const __attribute__((address_space(1))) void*)(g),                      \
        (__attribute__((address_space(3))) void*)(l), 16, 0, 0)

#define WAITV(n) asm volatile("s_waitcnt vmcnt(" #n ")" ::: "memory")
#define BAR()    __builtin_amdgcn_s_barrier()
#define SCHEDB() __builtin_amdgcn_sched_barrier(0)

// ---------------- fp32 -> bf16 conversion (vectorized, grid-stride) ----------------
__global__ __launch_bounds__(256) void cvt_f32_bf16(
    const float* __restrict__ src, bf16* __restrict__ dst, int n16)
{
    int idx = blockIdx.x * 256 + threadIdx.x;
    const int stride = gridDim.x * 256;
    for (int i = idx; i < n16; i += stride) {
        const float* p = src + (size_t)i * 16;
        f32x4 a = *(const f32x4*)p;
        f32x4 b = *(const f32x4*)(p + 4);
        f32x4 c = *(const f32x4*)(p + 8);
        f32x4 d = *(const f32x4*)(p + 12);
        bf16x8 h0, h1;
#pragma unroll
        for (int j = 0; j < 4; ++j) {
            h0[j] = (bf16)a[j]; h0[4 + j] = (bf16)b[j];
            h1[j] = (bf16)c[j]; h1[4 + j] = (bf16)d[j];
        }
        bf16* q = dst + (size_t)i * 16;
        *(bf16x8*)q = h0;
        *(bf16x8*)(q + 8) = h1;
    }
}

// ---- single-phase 3-deep pipelined GEMM: C[M][N] = A[M][K]*B[N][K]^T + bias ----
// BM=128, BN=256, BK=64, 8 waves (2M x 4N -> per-wave 64x64, reuse=32).
// Per K-tile: {16 ds_read_b128 || stage tile t+2 (6 gloads)} -> 32 MFMA -> vmcnt(6) -> bar.
// 3 LDS buffers x 48KB = 144KB; counted vmcnt never drains mid-loop (retires t+1,
// leaves t+2 in flight). Hazards: buf (t+2)%3 was read in iter t-1, whose reads retired
// before that iter's barrier (MFMA lgkm-consumed); RAW guarded by vmcnt(6)+bar.
// Swizzle (r6-verified 0-conflict): phys 16B-slot s of row r holds chunk s^(r&7);
// staged via pre-swizzled global col; read slot (kk*4+hi)^(lo&7).
// Block map (nbx%16==0): 256-block window = 16 bx x 16 by; XCD owns 2 bx (4MB = L2) x 16 by.
template <int OUT_BF16>
__global__ __launch_bounds__(512, 2) void gemm_sp(
    const bf16* __restrict__ A, const bf16* __restrict__ B,
    const float* __restrict__ bias, void* __restrict__ Cout,
    int K, int ldc, int nbx)
{
    constexpr int ASZ = 128 * 64;              // 8192 elems
    constexpr int BUF = ASZ + 256 * 64;        // 24576 elems = 48KB
    __shared__ bf16 lds[3 * BUF];              // 144KB

    int bx, by;
    if ((nbx & 15) == 0) {
        const int r = (int)blockIdx.x & 255;
        const int slot = r >> 3;                                   // 0..31
        bx = ((int)blockIdx.x >> 8) * 16 + (r & 7) * 2 + (slot >> 4);
        by = slot & 15;
    } else {                                                       // fallback: XCD-chunked
        const int cpx = gridDim.x >> 3;
        const int swz = ((int)blockIdx.x & 7) * cpx + ((int)blockIdx.x >> 3);
        bx = swz % nbx; by = swz / nbx;
    }
    const int brow = by * 128, bcol = bx * 256;

    const int tid  = threadIdx.x;
    const int wv   = tid >> 6, lane = tid & 63;
    const int lo   = lane & 15, hi = lane >> 4;
    const int wrp  = wv >> 2, wcp = wv & 3;           // 2(M) x 4(N); per-wave 64 rows x 64 cols

    const int srow = lane >> 3;                       // row-in-chunk 0..7
    const int scol = ((lane & 7) ^ (lane >> 3)) * 8;  // pre-swizzled global col (elems)

    f32x4 acc[4][4];
#pragma unroll
    for (int m = 0; m < 4; ++m)
#pragma unroll
        for (int n = 0; n < 4; ++n)
            acc[m][n] = (f32x4){0.f, 0.f, 0.f, 0.f};

    // stage whole K-tile t into buf t%3: A 16 chunks (2/wave), B 32 chunks (4/wave); 6 gloads/wave
    auto STAGE = [&](int t) {
        const int k0 = t * 64;
        bf16* lb = &lds[(t % 3) * BUF];
#pragma unroll
        for (int j = 0; j < 2; ++j) {
            const int c = wv * 2 + j;
            GLOAD_LDS16(A + (size_t)(brow + c * 8 + srow) * K + k0 + scol, lb + c * 512);
        }
#pragma unroll
        for (int j = 0; j < 4; ++j) {
            const int c = wv * 4 + j;
            GLOAD_LDS16(B + (size_t)(bcol + c * 8 + srow) * K + k0 + scol, lb + ASZ + c * 512);
        }
    };

    const int nt = K / 64;

    STAGE(0); STAGE(1);
    WAITV(6); BAR(); SCHEDB();

    for (int t = 0; t < nt; ++t) {
        const bf16* lb = &lds[(t % 3) * BUF];

        bf16x8 af[4][2], bfr[4][2];
#pragma unroll
        for (int m = 0; m < 4; ++m) {
            const int ru = wrp * 64 + m * 16 + lo;
#pragma unroll
            for (int kk = 0; kk < 2; ++kk)
                af[m][kk] = *(const bf16x8*)&lb[ru * 64 + (((kk * 4 + hi) ^ (lo & 7)) * 8)];
        }
#pragma unroll
        for (int n = 0; n < 4; ++n) {
            const int rb = wcp * 64 + n * 16 + lo;
#pragma unroll
            for (int kk = 0; kk < 2; ++kk)
                bfr[n][kk] = *(const bf16x8*)&lb[ASZ + rb * 64 + (((kk * 4 + hi) ^ (lo & 7)) * 8)];
        }

        if (t + 2 < nt) STAGE(t + 2);    // issue early; lands under MFMA of this + next iter

        __builtin_amdgcn_s_setprio(1);
#pragma unroll
        for (int m = 0; m < 4; ++m)
#pragma unroll
            for (int n = 0; n < 4; ++n)
#pragma unroll
                for (int kk = 0; kk < 2; ++kk)
                    acc[m][n] = __builtin_amdgcn_mfma_f32_16x16x32_bf16(af[m][kk], bfr[n][kk], acc[m][n], 0, 0, 0);
        __builtin_amdgcn_s_setprio(0);

        if (t + 2 < nt)      WAITV(6);   // retire tile t+1; t+2 stays in flight
        else if (t + 1 < nt) WAITV(0);   // tail: last tile must be fully landed
        if (t + 1 < nt) { BAR(); SCHEDB(); }
    }

    // epilogue: C/D layout row=(lane>>4)*4+r, col=lane&15
#pragma unroll
    for (int m = 0; m < 4; ++m) {
        const int row = brow + wrp * 64 + m * 16 + hi * 4;
#pragma unroll
        for (int n = 0; n < 4; ++n) {
            const int col = bcol + wcp * 64 + n * 16 + lo;
            const float bv = bias[col];
#pragma unroll
            for (int r = 0; r < 4; ++r) {
                const float v = acc[m][n][r] + bv;
                if (OUT_BF16)
                    ((bf16*)Cout)[(size_t)(row + r) * ldc + col] = (bf16)v;
                else
                    ((float*)Cout)[(size_t)(row + r) * ldc + col] = v;
            }
        }
    }
}

// ---------------- MFMA flash attention: causal + ALiBi, bf16 in/out (r6-verified) ----------------
__global__ __launch_bounds__(512) void attn_mfma(
    const bf16* __restrict__ qkv, bf16* __restrict__ attn_out)
{
    const int S = 2048, QKV = 12288, D = 4096, HD = 128;
    const int bid = blockIdx.x;
    const int h   = bid & 31;
    const int qi  = 15 - (bid >> 5);
    const int q0  = qi * 128;
    const int tid = threadIdx.x;
    const int w    = tid >> 6, lane = tid & 63;
    const int lo   = lane & 15, hi = lane >> 4;
    const int qbase = q0 + w * 16;

    __shared__ bf16 Ks[64 * 128];
    __shared__ bf16 Vs[128 * 72];
    __shared__ bf16 Ps[8 * 16 * 72];

    const float scale = 0.08838834764831845f;
    const float slope = exp2f(-0.25f * (float)(h + 1));

    bf16x8 qfrag[4];
#pragma unroll
    for (int ds = 0; ds < 4; ++ds)
        qfrag[ds] = *(const bf16x8*)(qkv + (size_t)(qbase + lo) * QKV + h * HD + ds * 32 + hi * 8);

    f32x4 o[8];
#pragma unroll
    for (int dt = 0; dt < 8; ++dt) o[dt] = (f32x4){0.f, 0.f, 0.f, 0.f};
    float mrow[4] = {-1e30f, -1e30f, -1e30f, -1e30f};
    float lrow[4] = {0.f, 0.f, 0.f, 0.f};

    const int krow = tid >> 3;
    const int kch  = tid & 7;
    const int vp2  = tid & 63;
    const int voct = tid >> 6;

    const int ntile = (q0 + 128) / 64;
    for (int t = 0; t < ntile; ++t) {
        const int kv0 = t * 64;
        {
            const bf16* kp = qkv + (size_t)(kv0 + krow) * QKV + D + h * HD + kch * 16;
            bf16x8 k0 = *(const bf16x8*)kp;
            bf16x8 k1 = *(const bf16x8*)(kp + 8);
            const int kb  = krow * 128 + kch * 16;
            const int swzk = (krow & 7) << 3;
            *(bf16x8*)&Ks[kb ^ swzk]       = k0;
            *(bf16x8*)&Ks[(kb + 8) ^ swzk] = k1;
        }
        {
            const bf16* vp = qkv + (size_t)(kv0 + voct * 8) * QKV + 2 * D + h * HD + 2 * vp2;
            bf16x8 r0, r1;
#pragma unroll
            for (int j = 0; j < 8; ++j) {
                const unsigned u = *(const unsigned*)(vp + (size_t)j * QKV);
                unsigned short us0 = (unsigned short)(u & 0xffff);
                unsigned short us1 = (unsigned short)(u >> 16);
                r0[j] = *(const bf16*)&us0;
                r1[j] = *(const bf16*)&us1;
            }
            *(bf16x8*)&Vs[(2 * vp2) * 72 + voct * 8]     = r0;
            *(bf16x8*)&Vs[(2 * vp2 + 1) * 72 + voct * 8] = r1;
        }
        __syncthreads();

        if (kv0 <= qbase + 15) {
            f32x4 c[4];
#pragma unroll
            for (int j = 0; j < 4; ++j) c[j] = (f32x4){0.f, 0.f, 0.f, 0.f};
            __builtin_amdgcn_s_setprio(1);
#pragma unroll
            for (int ds = 0; ds < 4; ++ds) {
#pragma unroll
                for (int j = 0; j < 4; ++j) {
                    const int r = j * 16 + lo;
                    bf16x8 b = *(const bf16x8*)&Ks[(r * 128 + ds * 32 + hi * 8) ^ ((r & 7) << 3)];
                    c[j] = __builtin_amdgcn_mfma_f32_16x16x32_bf16(qfrag[ds], b, c[j], 0, 0, 0);
                }
            }
            __builtin_amdgcn_s_setprio(0);
#pragma unroll
            for (int r = 0; r < 4; ++r) {
                const int q = qbase + hi * 4 + r;
                float s[4];
#pragma unroll
                for (int j = 0; j < 4; ++j) {
                    const int ki = kv0 + j * 16 + lo;
                    s[j] = c[j][r] * scale + slope * (float)(ki - (S - 1));
                    if (ki > q) s[j] = -1e30f;
                }
                float tm = fmaxf(fmaxf(s[0], s[1]), fmaxf(s[2], s[3]));
                tm = fmaxf(tm, __shfl_xor(tm, 1));
                tm = fmaxf(tm, __shfl_xor(tm, 2));
                tm = fmaxf(tm, __shfl_xor(tm, 4));
                tm = fmaxf(tm, __shfl_xor(tm, 8));
                const float mnew = fmaxf(mrow[r], tm);
                const float cr = __expf(mrow[r] - mnew);
                float p[4], ps = 0.f;
#pragma unroll
                for (int j = 0; j < 4; ++j) { p[j] = __expf(s[j] - mnew); ps += p[j]; }
                ps += __shfl_xor(ps, 1);
                ps += __shfl_xor(ps, 2);
                ps += __shfl_xor(ps, 4);
                ps += __shfl_xor(ps, 8);
                lrow[r] = lrow[r] * cr + ps;
                mrow[r] = mnew;
#pragma unroll
                for (int dt = 0; dt < 8; ++dt) o[dt][r] *= cr;
#pragma unroll
                for (int j = 0; j < 4; ++j)
                    Ps[w * 1152 + (hi * 4 + r) * 72 + j * 16 + lo] = (bf16)p[j];
            }
            bf16x8 pa0 = *(const bf16x8*)&Ps[w * 1152 + lo * 72 + hi * 8];
            bf16x8 pa1 = *(const bf16x8*)&Ps[w * 1152 + lo * 72 + 32 + hi * 8];
            __builtin_amdgcn_s_setprio(1);
#pragma unroll
            for (int dt = 0; dt < 8; ++dt) {
                bf16x8 bv0 = *(const bf16x8*)&Vs[(dt * 16 + lo) * 72 + hi * 8];
                bf16x8 bv1 = *(const bf16x8*)&Vs[(dt * 16 + lo) * 72 + 32 + hi * 8];
                o[dt] = __builtin_amdgcn_mfma_f32_16x16x32_bf16(pa0, bv0, o[dt], 0, 0, 0);
                o[dt] = __builtin_amdgcn_mfma_f32_16x16x32_bf16(pa1, bv1, o[dt], 0, 0, 0);
            }
            __builtin_amdgcn_s_setprio(0);
        }
        __syncthreads();
    }

#pragma unroll
    for (int r = 0; r < 4; ++r) {
        const float inv = 1.0f / lrow[r];
        const int q = qbase + hi * 4 + r;
        bf16* op = attn_out + (size_t)q * D + h * HD;
#pragma unroll
        for (int dt = 0; dt < 8; ++dt)
            op[dt * 16 + lo] = (bf16)(o[dt][r] * inv);
    }
}

extern "C" void kernel_launch(void* const* d_in, const int* in_sizes, int n_in,
                              void* d_out, int out_size, void* d_ws, size_t ws_size,
                              hipStream_t stream) {
    const int S = 2048, D = 4096, QKV = 12288;
    const int NH = 6144;
    const float* x     = (const float*)d_in[0];
    const float* w_qkv = (const float*)d_in[1];
    const float* b_qkv = (const float*)d_in[2];
    const float* w_out = (const float*)d_in[3];
    const float* b_out = (const float*)d_in[4];
    float* out = (float*)d_out;

    char* ws = (char*)d_ws;
    const size_t need_full = (size_t)S * D * 2 + (size_t)QKV * D * 2 + (size_t)S * QKV * 2;

    if (ws_size >= need_full) {
        bf16* xb    = (bf16*)ws;                                    // [2048][4096]
        bf16* attnb = xb;                                           // reuse after xb dead
        bf16* wqb   = (bf16*)(ws + (size_t)S * D * 2);              // [12288][4096]
        bf16* wob   = wqb;                                          // reuse after wqb dead
        bf16* qkvb  = (bf16*)(ws + (size_t)S * D * 2 + (size_t)QKV * D * 2);  // [2048][12288]

        cvt_f32_bf16<<<2048, 256, 0, stream>>>(x, xb, S * D / 16);
        cvt_f32_bf16<<<4096, 256, 0, stream>>>(w_qkv, wqb, QKV * D / 16);
        gemm_sp<1><<<(QKV / 256) * (S / 128), 512, 0, stream>>>(xb, wqb, b_qkv, qkvb, D, QKV, QKV / 256);
        attn_mfma<<<512, 512, 0, stream>>>(qkvb, attnb);
        cvt_f32_bf16<<<2048, 256, 0, stream>>>(w_out, wob, D * D / 16);
        gemm_sp<0><<<(D / 256) * (S / 128), 512, 0, stream>>>(attnb, wob, b_out, out, D, D, D / 256);
    } else {
        bf16* xb    = (bf16*)ws;
        bf16* attnb = xb;
        bf16* wb    = (bf16*)(ws + (size_t)S * D * 2);              // [6144][4096]
        bf16* wob   = wb;
        bf16* qkvb  = (bf16*)(ws + (size_t)S * D * 2 + (size_t)NH * D * 2);

        cvt_f32_bf16<<<2048, 256, 0, stream>>>(x, xb, S * D / 16);
        cvt_f32_bf16<<<2048, 256, 0, stream>>>(w_qkv, wb, NH * D / 16);
        gemm_sp<1><<<(NH / 256) * (S / 128), 512, 0, stream>>>(xb, wb, b_qkv, qkvb, D, QKV, NH / 256);
        cvt_f32_bf16<<<2048, 256, 0, stream>>>(w_qkv + (size_t)NH * D, wb, NH * D / 16);
        gemm_sp<1><<<(NH / 256) * (S / 128), 512, 0, stream>>>(xb, wb, b_qkv + NH, qkvb + NH, D, QKV, NH / 256);
        attn_mfma<<<512, 512, 0, stream>>>(qkvb, attnb);
        cvt_f32_bf16<<<2048, 256, 0, stream>>>(w_out, wob, D * D / 16);
        gemm_sp<0><<<(D / 256) * (S / 128), 512, 0, stream>>>(attnb, wob, b_out, out, D, D, D / 256);
    }
}